// Round 10
// baseline (164.038 us; speedup 1.0000x reference)
//
#include <hip/hip_runtime.h>
#include <math.h>

// ---------------------------------------------------------------------------
// N=4, T=2048, D_MODEL=512, NHEAD=8, HEAD_DIM=64, window -127..+128.
// Pipeline (3 launches): qkv = x@Wqkv^T + fused RoPE + q-scale (MFMA, fp32
// operands converted to bf16 in staging registers) ; flash attn (MFMA) ;
// out = attn@out_w^T + b (MFMA, out_w converted in staging).
// R10: cvt_all deleted — fp32->bf16 RNE pack happens during LDS staging
// (g1 is LDS-pipe bound, so the extra fp32 global reads hide). Attn reverted
// to R8 form (R9 prefetch was neutral) + fully-masked QK sub-tile skip.
// ---------------------------------------------------------------------------

typedef __attribute__((ext_vector_type(8))) __bf16 bf16x8;
typedef __attribute__((ext_vector_type(4))) float f32x4;

__device__ __forceinline__ unsigned short f2bf(float f) {
    unsigned int u = __float_as_uint(f);
    u += 0x7fffu + ((u >> 16) & 1u);
    return (unsigned short)(u >> 16);
}
__device__ __forceinline__ unsigned int packbf2(float a, float b) {
    unsigned int ua = __float_as_uint(a); ua += 0x7fffu + ((ua >> 16) & 1u);
    unsigned int ub = __float_as_uint(b); ub += 0x7fffu + ((ub >> 16) & 1u);
    return (ua >> 16) | (ub & 0xffff0000u);
}
__device__ __forceinline__ bf16x8 as_bf16x8(uint4 u) {
    union { uint4 u4; bf16x8 v; } c; c.u4 = u; return c.v;
}
__device__ __forceinline__ bf16x8 ld_frag(const unsigned short* p) {
    return as_bf16x8(*(const uint4*)p);
}
__device__ __forceinline__ uint4 pack8(const float4& a, const float4& b) {
    uint4 o;
    o.x = packbf2(a.x, a.y);
    o.y = packbf2(a.z, a.w);
    o.z = packbf2(b.x, b.y);
    o.w = packbf2(b.z, b.w);
    return o;
}

// C[M,O] = A[M,K] * B[O,K]^T (+bias). A/B are bf16 (ushort) or fp32 per
// template flag; fp32 operands are RNE-packed to bf16 in staging registers.
// BM=128, BN=64, BK=64. Block=256 (4 waves); wave w computes rows
// [w*32,+32) x all 64 cols (mt=2, nt=4; acc 32 AGPR).
// LDS XOR-swizzled k-offset: frag reads conflict-free.
// do_rope: qkv layout (O=1536); RoPE cols<1024 (partner col^32 == acc nt^2,
// same thread), fold 1/8 into q cols<512.
template<int AF32, int BF32>
__global__ __launch_bounds__(256) void gemm_bt_mfma(
    const void* __restrict__ Av, const void* __restrict__ Bv,
    const float* __restrict__ bias, void* __restrict__ Cout,
    int M, int O, int K, int write_bf16, int do_rope)
{
    __shared__ __align__(16) unsigned short As[128 * 64];   // 16 KB
    __shared__ __align__(16) unsigned short Bs[64 * 64];    // 8 KB

    const int tid  = threadIdx.x;
    const int wave = tid >> 6;
    const int lane = tid & 63;
    const int l15  = lane & 15;
    const int lg   = lane >> 4;
    const int row0 = blockIdx.x * 128;
    const int col0 = blockIdx.y * 64;
    const int wr   = wave * 32;

    f32x4 acc[2][4] = {};

    // staging: chunk s -> row = s*32 + (tid>>3); lds k = (tid&7)*8;
    // global k = lds_k ^ ((row&7)*8)  (XOR swizzle, row&7 same for all s)
    const int srow = tid >> 3;
    const int ldk  = (tid & 7) * 8;
    const int skg  = ldk ^ ((srow & 7) * 8);
    // frag read swizzle: row&7 == l15&7 (wr, mt*16, nt*16 multiples of 8)
    const int fx   = (l15 & 7) * 8;

    for (int k0 = 0; k0 < K; k0 += 64) {
        // ---- load phase (all global loads issued before packing) ----
        uint4 a_st[4], b_st[2];
        if (AF32) {
            const float* A = (const float*)Av;
            float4 f[4][2];
            #pragma unroll
            for (int s = 0; s < 4; ++s) {
                const float* p = A + (size_t)(row0 + s * 32 + srow) * K + k0 + skg;
                f[s][0] = ((const float4*)p)[0];
                f[s][1] = ((const float4*)p)[1];
            }
            #pragma unroll
            for (int s = 0; s < 4; ++s) a_st[s] = pack8(f[s][0], f[s][1]);
        } else {
            const unsigned short* A = (const unsigned short*)Av;
            #pragma unroll
            for (int s = 0; s < 4; ++s)
                a_st[s] = *(const uint4*)(A + (size_t)(row0 + s * 32 + srow) * K + k0 + skg);
        }
        if (BF32) {
            const float* B = (const float*)Bv;
            float4 f[2][2];
            #pragma unroll
            for (int s = 0; s < 2; ++s) {
                const float* p = B + (size_t)(col0 + s * 32 + srow) * K + k0 + skg;
                f[s][0] = ((const float4*)p)[0];
                f[s][1] = ((const float4*)p)[1];
            }
            #pragma unroll
            for (int s = 0; s < 2; ++s) b_st[s] = pack8(f[s][0], f[s][1]);
        } else {
            const unsigned short* B = (const unsigned short*)Bv;
            #pragma unroll
            for (int s = 0; s < 2; ++s)
                b_st[s] = *(const uint4*)(B + (size_t)(col0 + s * 32 + srow) * K + k0 + skg);
        }

        // ---- LDS write phase (previous iter's reads fenced by barrier 2) ----
        #pragma unroll
        for (int s = 0; s < 4; ++s)
            *(uint4*)&As[(s * 32 + srow) * 64 + ldk] = a_st[s];
        #pragma unroll
        for (int s = 0; s < 2; ++s)
            *(uint4*)&Bs[(s * 32 + srow) * 64 + ldk] = b_st[s];
        __syncthreads();   // barrier 1: staging visible

        #pragma unroll
        for (int kstep = 0; kstep < 2; ++kstep) {
            const int kq = (kstep * 32 + lg * 8) ^ fx;
            bf16x8 af[2], bfr[4];
            #pragma unroll
            for (int mt = 0; mt < 2; ++mt)
                af[mt] = ld_frag(&As[(wr + mt * 16 + l15) * 64 + kq]);
            #pragma unroll
            for (int nt = 0; nt < 4; ++nt)
                bfr[nt] = ld_frag(&Bs[(nt * 16 + l15) * 64 + kq]);
            #pragma unroll
            for (int mt = 0; mt < 2; ++mt)
                #pragma unroll
                for (int nt = 0; nt < 4; ++nt)
                    acc[mt][nt] = __builtin_amdgcn_mfma_f32_16x16x32_bf16(
                        af[mt], bfr[nt], acc[mt][nt], 0, 0, 0);
        }
        __syncthreads();   // barrier 2: reads done before restage
    }

    const int qrow = lg * 4;

    // Fused RoPE: col = col0 + nt*16 + l15, col0 mult of 64 -> d = nt*16+l15.
    // i = d&31 -> (nt&1)*16+l15 ; partner d^32 = acc nt^2 (same thread).
    if (do_rope && col0 < 1024) {
        const float cfreq = 0.28782313662425574f;   // ln(10000)/32
        const float invf0 = __expf(-(float)l15 * cfreq);
        const float invf1 = __expf(-(float)(16 + l15) * cfreq);
        #pragma unroll
        for (int mt = 0; mt < 2; ++mt) {
            #pragma unroll
            for (int r = 0; r < 4; ++r) {
                const int t = (row0 + wr + mt * 16 + qrow + r) & 2047;
                #pragma unroll
                for (int p = 0; p < 2; ++p) {
                    float ang = (float)t * (p ? invf1 : invf0);
                    float s, c;
                    __sincosf(ang, &s, &c);
                    float a = acc[mt][p][r];       // d = p*16+l15 (< 32)
                    float b = acc[mt][p + 2][r];   // d = 32 + p*16+l15
                    acc[mt][p][r]     = a * c - b * s;
                    acc[mt][p + 2][r] = b * c + a * s;
                }
            }
        }
        if (col0 < 512) {   // q: fold softmax scale 1/sqrt(64)
            #pragma unroll
            for (int mt = 0; mt < 2; ++mt)
                #pragma unroll
                for (int nt = 0; nt < 4; ++nt)
                    #pragma unroll
                    for (int r = 0; r < 4; ++r)
                        acc[mt][nt][r] *= 0.125f;
        }
    }

    #pragma unroll
    for (int nt = 0; nt < 4; ++nt) {
        const int col = col0 + nt * 16 + l15;
        const float bv = bias ? bias[col] : 0.f;
        #pragma unroll
        for (int mt = 0; mt < 2; ++mt) {
            const int rowb = row0 + wr + mt * 16 + qrow;
            if (write_bf16) {
                unsigned short* C = (unsigned short*)Cout;
                #pragma unroll
                for (int r = 0; r < 4; ++r)
                    C[(size_t)(rowb + r) * O + col] = f2bf(acc[mt][nt][r] + bv);
            } else {
                float* C = (float*)Cout;
                #pragma unroll
                for (int r = 0; r < 4; ++r)
                    C[(size_t)(rowb + r) * O + col] = acc[mt][nt][r] + bv;
            }
        }
    }
}

// Flash attention with MFMA (R8 structure). Block=256 (4 waves) handles
// (qt, h, n). K staged (copy), V staged transposed; P via per-wave LDS slice.
// q pre-scaled by 1/8. Fully-masked QK sub-tiles skipped (dt=+-2 edges).
__global__ __launch_bounds__(256) void attn_mfma_kernel(
    const unsigned short* __restrict__ qkv, unsigned short* __restrict__ attnout)
{
    __shared__ __align__(16) unsigned short Kt[64 * 72];      // [key][dim]
    __shared__ __align__(16) unsigned short Vt[64 * 72];      // [dim][key]
    __shared__ __align__(16) unsigned short Ps[4][16 * 72];   // per-wave P

    const int qt = blockIdx.x;
    const int h  = blockIdx.y;
    const int n  = blockIdx.z;
    const int t0 = qt * 64;
    const int tid  = threadIdx.x;
    const int wave = tid >> 6;
    const int lane = tid & 63;
    const int l15  = lane & 15;
    const int lg   = lane >> 4;

    const size_t base = (size_t)n * 2048 * 1536 + (size_t)h * 64;

    bf16x8 qfrag[2];
    {
        const unsigned short* qp = qkv + base + (size_t)(t0 + wave * 16 + l15) * 1536;
        qfrag[0] = ld_frag(qp + lg * 8);
        qfrag[1] = ld_frag(qp + 32 + lg * 8);
    }

    const int skey = tid >> 2;
    const int sd0  = (tid & 3) * 16;

    float m_r[4], l_r[4];
    #pragma unroll
    for (int r = 0; r < 4; ++r) { m_r[r] = -1e30f; l_r[r] = 0.f; }
    f32x4 acc_o[4] = {};

    for (int dt = -2; dt <= 2; ++dt) {
        const int kt = qt + dt;
        if (kt < 0 || kt > 31) continue;
        const int s0 = kt * 64;

        {   // stage K (copy) + V (transpose)
            const unsigned short* kp = qkv + base + 512 + (size_t)(s0 + skey) * 1536 + sd0;
            uint4 k0 = *(const uint4*)kp;
            uint4 k1 = *(const uint4*)(kp + 8);
            *(uint4*)&Kt[skey * 72 + sd0]     = k0;
            *(uint4*)&Kt[skey * 72 + sd0 + 8] = k1;

            const unsigned short* vp = qkv + base + 1024 + (size_t)(s0 + skey) * 1536 + sd0;
            uint4 a = *(const uint4*)vp;
            uint4 b = *(const uint4*)(vp + 8);
            Vt[(sd0 +  0) * 72 + skey] = (unsigned short)(a.x & 0xffffu);
            Vt[(sd0 +  1) * 72 + skey] = (unsigned short)(a.x >> 16);
            Vt[(sd0 +  2) * 72 + skey] = (unsigned short)(a.y & 0xffffu);
            Vt[(sd0 +  3) * 72 + skey] = (unsigned short)(a.y >> 16);
            Vt[(sd0 +  4) * 72 + skey] = (unsigned short)(a.z & 0xffffu);
            Vt[(sd0 +  5) * 72 + skey] = (unsigned short)(a.z >> 16);
            Vt[(sd0 +  6) * 72 + skey] = (unsigned short)(a.w & 0xffffu);
            Vt[(sd0 +  7) * 72 + skey] = (unsigned short)(a.w >> 16);
            Vt[(sd0 +  8) * 72 + skey] = (unsigned short)(b.x & 0xffffu);
            Vt[(sd0 +  9) * 72 + skey] = (unsigned short)(b.x >> 16);
            Vt[(sd0 + 10) * 72 + skey] = (unsigned short)(b.y & 0xffffu);
            Vt[(sd0 + 11) * 72 + skey] = (unsigned short)(b.y >> 16);
            Vt[(sd0 + 12) * 72 + skey] = (unsigned short)(b.z & 0xffffu);
            Vt[(sd0 + 13) * 72 + skey] = (unsigned short)(b.z >> 16);
            Vt[(sd0 + 14) * 72 + skey] = (unsigned short)(b.w & 0xffffu);
            Vt[(sd0 + 15) * 72 + skey] = (unsigned short)(b.w >> 16);
        }
        __syncthreads();

        // ---- S = Q K^T (skip fully-masked sub-tiles at window edges) ----
        f32x4 acc_s[4] = {};
        #pragma unroll
        for (int kstep = 0; kstep < 2; ++kstep) {
            #pragma unroll
            for (int nt = 0; nt < 4; ++nt) {
                if ((dt == -2 && nt < wave) || (dt == 2 && nt > wave)) continue;
                bf16x8 kf = ld_frag(&Kt[(nt * 16 + l15) * 72 + kstep * 32 + lg * 8]);
                acc_s[nt] = __builtin_amdgcn_mfma_f32_16x16x32_bf16(
                    qfrag[kstep], kf, acc_s[nt], 0, 0, 0);
            }
        }

        float sc[4][4];
        #pragma unroll
        for (int nt = 0; nt < 4; ++nt) {
            const int key_off = dt * 64 + nt * 16 + l15;
            #pragma unroll
            for (int r = 0; r < 4; ++r) {
                const int diff = key_off - (wave * 16 + lg * 4 + r);
                const bool ok = (diff >= -127) && (diff <= 128);
                sc[nt][r] = ok ? acc_s[nt][r] : -1e30f;   // scale folded into q
            }
        }
        #pragma unroll
        for (int r = 0; r < 4; ++r) {
            float tm = fmaxf(fmaxf(sc[0][r], sc[1][r]), fmaxf(sc[2][r], sc[3][r]));
            tm = fmaxf(tm, __shfl_xor(tm, 1, 64));
            tm = fmaxf(tm, __shfl_xor(tm, 2, 64));
            tm = fmaxf(tm, __shfl_xor(tm, 4, 64));
            tm = fmaxf(tm, __shfl_xor(tm, 8, 64));
            const float m_new = fmaxf(m_r[r], tm);
            const float alpha = __expf(m_r[r] - m_new);
            float psum = 0.f;
            #pragma unroll
            for (int nt = 0; nt < 4; ++nt) {
                float p = __expf(sc[nt][r] - m_new);
                sc[nt][r] = p;
                psum += p;
            }
            psum += __shfl_xor(psum, 1, 64);
            psum += __shfl_xor(psum, 2, 64);
            psum += __shfl_xor(psum, 4, 64);
            psum += __shfl_xor(psum, 8, 64);
            l_r[r] = l_r[r] * alpha + psum;
            m_r[r] = m_new;
            #pragma unroll
            for (int nt = 0; nt < 4; ++nt) acc_o[nt][r] *= alpha;
        }

        #pragma unroll
        for (int nt = 0; nt < 4; ++nt)
            #pragma unroll
            for (int r = 0; r < 4; ++r)
                Ps[wave][(lg * 4 + r) * 72 + nt * 16 + l15] = f2bf(sc[nt][r]);

        __syncthreads();

        bf16x8 pfrag[2];
        pfrag[0] = ld_frag(&Ps[wave][l15 * 72 + lg * 8]);
        pfrag[1] = ld_frag(&Ps[wave][l15 * 72 + 32 + lg * 8]);

        #pragma unroll
        for (int kstep = 0; kstep < 2; ++kstep) {
            #pragma unroll
            for (int nt = 0; nt < 4; ++nt) {
                bf16x8 vf = ld_frag(&Vt[(nt * 16 + l15) * 72 + kstep * 32 + lg * 8]);
                acc_o[nt] = __builtin_amdgcn_mfma_f32_16x16x32_bf16(
                    pfrag[kstep], vf, acc_o[nt], 0, 0, 0);
            }
        }
        __syncthreads();
    }

    float inv_l[4];
    #pragma unroll
    for (int r = 0; r < 4; ++r) inv_l[r] = 1.0f / l_r[r];

    #pragma unroll
    for (int r = 0; r < 4; ++r) {
        const int tq = t0 + wave * 16 + lg * 4 + r;
        unsigned short* op = attnout + (size_t)(n * 2048 + tq) * 512 + h * 64;
        #pragma unroll
        for (int nt = 0; nt < 4; ++nt)
            op[nt * 16 + l15] = f2bf(acc_o[nt][r] * inv_l[r]);
    }
}

extern "C" void kernel_launch(void* const* d_in, const int* in_sizes, int n_in,
                              void* d_out, int out_size, void* d_ws, size_t ws_size,
                              hipStream_t stream)
{
    (void)in_sizes; (void)n_in; (void)out_size; (void)ws_size;

    const float* x     = (const float*)d_in[0];
    const float* Wqkv  = (const float*)d_in[1];
    const float* out_w = (const float*)d_in[2];
    const float* out_b = (const float*)d_in[3];
    float* out = (float*)d_out;

    unsigned short* qkvb  = (unsigned short*)d_ws;          // 8192*1536 bf16
    unsigned short* attnb = qkvb + (size_t)8192 * 1536;     // 8192*512  bf16

    // 1) qkv = x @ Wqkv^T with fused RoPE + q-scale (fp32 inputs converted
    //    to bf16 during staging; bf16 out)
    gemm_bt_mfma<1, 1><<<dim3(64, 24), 256, 0, stream>>>(
        x, Wqkv, nullptr, qkvb, 8192, 1536, 512, 1, 1);
    // 2) flash attention -> attnb bf16
    attn_mfma_kernel<<<dim3(32, 8, 4), 256, 0, stream>>>(qkvb, attnb);
    // 3) out = attn @ out_w^T + out_b (A bf16, B converted in staging; fp32 out)
    gemm_bt_mfma<0, 1><<<dim3(64, 8), 256, 0, stream>>>(
        attnb, out_w, out_b, out, 8192, 512, 512, 0, 0);
}

// Round 11
// 142.923 us; speedup vs baseline: 1.1477x; 1.1477x over previous
//
#include <hip/hip_runtime.h>
#include <math.h>

// ---------------------------------------------------------------------------
// N=4, T=2048, D_MODEL=512, NHEAD=8, HEAD_DIM=64, window -127..+128.
// Pipeline: cvt_all -> bf16 ; qkv = x@Wqkv^T + fused RoPE + q-scale (MFMA,
// LDS-staged BM=128 BN=64 BK=64, XOR-swizzled, global_load_lds) ; flash attn
// (MFMA) ; out GEMM. R11: exact R8 kernels; grid launched col-block-fastest
// so co-resident blocks share the A-tile in L2 (R10's in-staging cvt reverted:
// it doubled FETCH_SIZE and lost the async-DMA staging path -> 164 µs).
// ---------------------------------------------------------------------------

typedef __attribute__((ext_vector_type(8))) __bf16 bf16x8;
typedef __attribute__((ext_vector_type(4))) float f32x4;

__device__ __forceinline__ unsigned short f2bf(float f) {
    unsigned int u = __float_as_uint(f);
    u += 0x7fffu + ((u >> 16) & 1u);
    return (unsigned short)(u >> 16);
}
__device__ __forceinline__ unsigned int packbf2(float a, float b) {
    unsigned int ua = __float_as_uint(a); ua += 0x7fffu + ((ua >> 16) & 1u);
    unsigned int ub = __float_as_uint(b); ub += 0x7fffu + ((ub >> 16) & 1u);
    return (ua >> 16) | (ub & 0xffff0000u);
}
__device__ __forceinline__ bf16x8 as_bf16x8(uint4 u) {
    union { uint4 u4; bf16x8 v; } c; c.u4 = u; return c.v;
}
__device__ __forceinline__ bf16x8 ld_frag(const unsigned short* p) {
    return as_bf16x8(*(const uint4*)p);
}

__device__ __forceinline__ void async16(void* lds, const void* g) {
    __builtin_amdgcn_global_load_lds(
        (const __attribute__((address_space(1))) void*)g,
        (__attribute__((address_space(3))) void*)lds,
        16, 0, 0);
}

// One kernel converts all three fp32 inputs to bf16 (4 elems/thread).
__global__ __launch_bounds__(256) void cvt_all(
    const float* __restrict__ x, const float* __restrict__ w1,
    const float* __restrict__ w2,
    unsigned short* __restrict__ xb, unsigned short* __restrict__ w1b,
    unsigned short* __restrict__ w2b)
{
    const int n_x  = 8192 * 512 / 4;
    const int n_w1 = 1536 * 512 / 4;
    const int n_w2 = 512 * 512 / 4;
    int i = blockIdx.x * 256 + threadIdx.x;
    const float* in; unsigned short* out; int j;
    if (i < n_x)                    { in = x;  out = xb;  j = i; }
    else if (i < n_x + n_w1)        { in = w1; out = w1b; j = i - n_x; }
    else if (i < n_x + n_w1 + n_w2) { in = w2; out = w2b; j = i - n_x - n_w1; }
    else return;
    float4 v = *(const float4*)(in + 4 * (size_t)j);
    uint2 o;
    o.x = packbf2(v.x, v.y);
    o.y = packbf2(v.z, v.w);
    *(uint2*)(out + 4 * (size_t)j) = o;
}

// C[M,O] = A[M,K](bf16) * B[O,K](bf16)^T (+bias). Output fp32 or bf16.
// BM=128, BN=64, BK=64. Block=256 (4 waves); wave w computes rows
// [w*32,+32) x all 64 cols (mt=2, nt=4; acc 32 AGPR).
// Grid: blockIdx.x = COL block (fastest -> L2 A-tile sharing), .y = ROW block.
// LDS XOR-swizzled k-offset: staging dests stay chunk-contiguous
// (global_load_lds constraint), frag reads conflict-free.
// do_rope: qkv layout (O=1536); RoPE cols<1024 (partner col^32 == acc nt^2,
// same thread), fold 1/8 into q cols<512.
__global__ __launch_bounds__(256) void gemm_bt_mfma(
    const unsigned short* __restrict__ A, const unsigned short* __restrict__ B,
    const float* __restrict__ bias, void* __restrict__ Cout,
    int M, int O, int K, int write_bf16, int do_rope)
{
    __shared__ __align__(16) unsigned short As[128 * 64];   // 16 KB
    __shared__ __align__(16) unsigned short Bs[64 * 64];    // 8 KB

    const int tid  = threadIdx.x;
    const int wave = tid >> 6;
    const int lane = tid & 63;
    const int l15  = lane & 15;
    const int lg   = lane >> 4;
    const int row0 = blockIdx.y * 128;
    const int col0 = blockIdx.x * 64;
    const int wr   = wave * 32;

    f32x4 acc[2][4] = {};

    // staging: chunk c = s*256 + tid -> row = s*32 + (tid>>3), lds k = (tid&7)*8
    // global k fetched = lds k ^ ((row&7)*8); row&7 == (tid>>3)&7 for all s.
    const int srow = tid >> 3;
    const int skg  = ((tid & 7) * 8) ^ ((srow & 7) * 8);
    // frag read swizzle: row&7 == l15&7 (wr, mt*16, nt*16 are multiples of 8)
    const int fx   = (l15 & 7) * 8;

    for (int k0 = 0; k0 < K; k0 += 64) {
        #pragma unroll
        for (int s = 0; s < 4; ++s)
            async16(&As[(size_t)(s * 256 + tid) * 8],
                    A + (size_t)(row0 + s * 32 + srow) * K + k0 + skg);
        #pragma unroll
        for (int s = 0; s < 2; ++s)
            async16(&Bs[(size_t)(s * 256 + tid) * 8],
                    B + (size_t)(col0 + s * 32 + srow) * K + k0 + skg);
        __syncthreads();

        #pragma unroll
        for (int kstep = 0; kstep < 2; ++kstep) {
            const int kq = (kstep * 32 + lg * 8) ^ fx;
            bf16x8 af[2], bfr[4];
            #pragma unroll
            for (int mt = 0; mt < 2; ++mt)
                af[mt] = ld_frag(&As[(wr + mt * 16 + l15) * 64 + kq]);
            #pragma unroll
            for (int nt = 0; nt < 4; ++nt)
                bfr[nt] = ld_frag(&Bs[(nt * 16 + l15) * 64 + kq]);
            #pragma unroll
            for (int mt = 0; mt < 2; ++mt)
                #pragma unroll
                for (int nt = 0; nt < 4; ++nt)
                    acc[mt][nt] = __builtin_amdgcn_mfma_f32_16x16x32_bf16(
                        af[mt], bfr[nt], acc[mt][nt], 0, 0, 0);
        }
        __syncthreads();
    }

    const int qrow = lg * 4;

    // Fused RoPE: col = col0 + nt*16 + l15, col0 mult of 64 -> d = nt*16+l15.
    // i = d&31 -> (nt&1)*16+l15 ; partner d^32 = acc nt^2 (same thread).
    if (do_rope && col0 < 1024) {
        const float cfreq = 0.28782313662425574f;   // ln(10000)/32
        const float invf0 = __expf(-(float)l15 * cfreq);
        const float invf1 = __expf(-(float)(16 + l15) * cfreq);
        #pragma unroll
        for (int mt = 0; mt < 2; ++mt) {
            #pragma unroll
            for (int r = 0; r < 4; ++r) {
                const int t = (row0 + wr + mt * 16 + qrow + r) & 2047;
                #pragma unroll
                for (int p = 0; p < 2; ++p) {
                    float ang = (float)t * (p ? invf1 : invf0);
                    float s, c;
                    __sincosf(ang, &s, &c);
                    float a = acc[mt][p][r];       // d = p*16+l15 (< 32)
                    float b = acc[mt][p + 2][r];   // d = 32 + p*16+l15
                    acc[mt][p][r]     = a * c - b * s;
                    acc[mt][p + 2][r] = b * c + a * s;
                }
            }
        }
        if (col0 < 512) {   // q: fold softmax scale 1/sqrt(64)
            #pragma unroll
            for (int mt = 0; mt < 2; ++mt)
                #pragma unroll
                for (int nt = 0; nt < 4; ++nt)
                    #pragma unroll
                    for (int r = 0; r < 4; ++r)
                        acc[mt][nt][r] *= 0.125f;
        }
    }

    #pragma unroll
    for (int nt = 0; nt < 4; ++nt) {
        const int col = col0 + nt * 16 + l15;
        const float bv = bias ? bias[col] : 0.f;
        #pragma unroll
        for (int mt = 0; mt < 2; ++mt) {
            const int rowb = row0 + wr + mt * 16 + qrow;
            if (write_bf16) {
                unsigned short* C = (unsigned short*)Cout;
                #pragma unroll
                for (int r = 0; r < 4; ++r)
                    C[(size_t)(rowb + r) * O + col] = f2bf(acc[mt][nt][r] + bv);
            } else {
                float* C = (float*)Cout;
                #pragma unroll
                for (int r = 0; r < 4; ++r)
                    C[(size_t)(rowb + r) * O + col] = acc[mt][nt][r] + bv;
            }
        }
    }
}

// Flash attention with MFMA (R8 structure + edge sub-tile skip). Block=256
// (4 waves) handles (qt, h, n). K staged (copy), V staged transposed; P via
// per-wave LDS slice. q pre-scaled by 1/8 in the QKV GEMM epilogue.
__global__ __launch_bounds__(256) void attn_mfma_kernel(
    const unsigned short* __restrict__ qkv, unsigned short* __restrict__ attnout)
{
    __shared__ __align__(16) unsigned short Kt[64 * 72];      // [key][dim]
    __shared__ __align__(16) unsigned short Vt[64 * 72];      // [dim][key]
    __shared__ __align__(16) unsigned short Ps[4][16 * 72];   // per-wave P

    const int qt = blockIdx.x;
    const int h  = blockIdx.y;
    const int n  = blockIdx.z;
    const int t0 = qt * 64;
    const int tid  = threadIdx.x;
    const int wave = tid >> 6;
    const int lane = tid & 63;
    const int l15  = lane & 15;
    const int lg   = lane >> 4;

    const size_t base = (size_t)n * 2048 * 1536 + (size_t)h * 64;

    bf16x8 qfrag[2];
    {
        const unsigned short* qp = qkv + base + (size_t)(t0 + wave * 16 + l15) * 1536;
        qfrag[0] = ld_frag(qp + lg * 8);
        qfrag[1] = ld_frag(qp + 32 + lg * 8);
    }

    const int skey = tid >> 2;
    const int sd0  = (tid & 3) * 16;

    float m_r[4], l_r[4];
    #pragma unroll
    for (int r = 0; r < 4; ++r) { m_r[r] = -1e30f; l_r[r] = 0.f; }
    f32x4 acc_o[4] = {};

    for (int dt = -2; dt <= 2; ++dt) {
        const int kt = qt + dt;
        if (kt < 0 || kt > 31) continue;
        const int s0 = kt * 64;

        {   // stage K (copy) + V (transpose)
            const unsigned short* kp = qkv + base + 512 + (size_t)(s0 + skey) * 1536 + sd0;
            uint4 k0 = *(const uint4*)kp;
            uint4 k1 = *(const uint4*)(kp + 8);
            *(uint4*)&Kt[skey * 72 + sd0]     = k0;
            *(uint4*)&Kt[skey * 72 + sd0 + 8] = k1;

            const unsigned short* vp = qkv + base + 1024 + (size_t)(s0 + skey) * 1536 + sd0;
            uint4 a = *(const uint4*)vp;
            uint4 b = *(const uint4*)(vp + 8);
            Vt[(sd0 +  0) * 72 + skey] = (unsigned short)(a.x & 0xffffu);
            Vt[(sd0 +  1) * 72 + skey] = (unsigned short)(a.x >> 16);
            Vt[(sd0 +  2) * 72 + skey] = (unsigned short)(a.y & 0xffffu);
            Vt[(sd0 +  3) * 72 + skey] = (unsigned short)(a.y >> 16);
            Vt[(sd0 +  4) * 72 + skey] = (unsigned short)(a.z & 0xffffu);
            Vt[(sd0 +  5) * 72 + skey] = (unsigned short)(a.z >> 16);
            Vt[(sd0 +  6) * 72 + skey] = (unsigned short)(a.w & 0xffffu);
            Vt[(sd0 +  7) * 72 + skey] = (unsigned short)(a.w >> 16);
            Vt[(sd0 +  8) * 72 + skey] = (unsigned short)(b.x & 0xffffu);
            Vt[(sd0 +  9) * 72 + skey] = (unsigned short)(b.x >> 16);
            Vt[(sd0 + 10) * 72 + skey] = (unsigned short)(b.y & 0xffffu);
            Vt[(sd0 + 11) * 72 + skey] = (unsigned short)(b.y >> 16);
            Vt[(sd0 + 12) * 72 + skey] = (unsigned short)(b.z & 0xffffu);
            Vt[(sd0 + 13) * 72 + skey] = (unsigned short)(b.z >> 16);
            Vt[(sd0 + 14) * 72 + skey] = (unsigned short)(b.w & 0xffffu);
            Vt[(sd0 + 15) * 72 + skey] = (unsigned short)(b.w >> 16);
        }
        __syncthreads();

        // ---- S = Q K^T (skip fully-masked edge sub-tiles) ----
        f32x4 acc_s[4] = {};
        #pragma unroll
        for (int kstep = 0; kstep < 2; ++kstep) {
            #pragma unroll
            for (int nt = 0; nt < 4; ++nt) {
                if ((dt == -2 && nt < wave) || (dt == 2 && nt > wave)) continue;
                bf16x8 kf = ld_frag(&Kt[(nt * 16 + l15) * 72 + kstep * 32 + lg * 8]);
                acc_s[nt] = __builtin_amdgcn_mfma_f32_16x16x32_bf16(
                    qfrag[kstep], kf, acc_s[nt], 0, 0, 0);
            }
        }

        float sc[4][4];
        #pragma unroll
        for (int nt = 0; nt < 4; ++nt) {
            const int key_off = dt * 64 + nt * 16 + l15;
            #pragma unroll
            for (int r = 0; r < 4; ++r) {
                const int diff = key_off - (wave * 16 + lg * 4 + r);
                const bool ok = (diff >= -127) && (diff <= 128);
                sc[nt][r] = ok ? acc_s[nt][r] : -1e30f;   // scale folded into q
            }
        }
        #pragma unroll
        for (int r = 0; r < 4; ++r) {
            float tm = fmaxf(fmaxf(sc[0][r], sc[1][r]), fmaxf(sc[2][r], sc[3][r]));
            tm = fmaxf(tm, __shfl_xor(tm, 1, 64));
            tm = fmaxf(tm, __shfl_xor(tm, 2, 64));
            tm = fmaxf(tm, __shfl_xor(tm, 4, 64));
            tm = fmaxf(tm, __shfl_xor(tm, 8, 64));
            const float m_new = fmaxf(m_r[r], tm);
            const float alpha = __expf(m_r[r] - m_new);
            float psum = 0.f;
            #pragma unroll
            for (int nt = 0; nt < 4; ++nt) {
                float p = __expf(sc[nt][r] - m_new);
                sc[nt][r] = p;
                psum += p;
            }
            psum += __shfl_xor(psum, 1, 64);
            psum += __shfl_xor(psum, 2, 64);
            psum += __shfl_xor(psum, 4, 64);
            psum += __shfl_xor(psum, 8, 64);
            l_r[r] = l_r[r] * alpha + psum;
            m_r[r] = m_new;
            #pragma unroll
            for (int nt = 0; nt < 4; ++nt) acc_o[nt][r] *= alpha;
        }

        #pragma unroll
        for (int nt = 0; nt < 4; ++nt)
            #pragma unroll
            for (int r = 0; r < 4; ++r)
                Ps[wave][(lg * 4 + r) * 72 + nt * 16 + l15] = f2bf(sc[nt][r]);

        __syncthreads();

        bf16x8 pfrag[2];
        pfrag[0] = ld_frag(&Ps[wave][l15 * 72 + lg * 8]);
        pfrag[1] = ld_frag(&Ps[wave][l15 * 72 + 32 + lg * 8]);

        #pragma unroll
        for (int kstep = 0; kstep < 2; ++kstep) {
            #pragma unroll
            for (int nt = 0; nt < 4; ++nt) {
                bf16x8 vf = ld_frag(&Vt[(nt * 16 + l15) * 72 + kstep * 32 + lg * 8]);
                acc_o[nt] = __builtin_amdgcn_mfma_f32_16x16x32_bf16(
                    pfrag[kstep], vf, acc_o[nt], 0, 0, 0);
            }
        }
        __syncthreads();
    }

    float inv_l[4];
    #pragma unroll
    for (int r = 0; r < 4; ++r) inv_l[r] = 1.0f / l_r[r];

    #pragma unroll
    for (int r = 0; r < 4; ++r) {
        const int tq = t0 + wave * 16 + lg * 4 + r;
        unsigned short* op = attnout + (size_t)(n * 2048 + tq) * 512 + h * 64;
        #pragma unroll
        for (int nt = 0; nt < 4; ++nt)
            op[nt * 16 + l15] = f2bf(acc_o[nt][r] * inv_l[r]);
    }
}

extern "C" void kernel_launch(void* const* d_in, const int* in_sizes, int n_in,
                              void* d_out, int out_size, void* d_ws, size_t ws_size,
                              hipStream_t stream)
{
    (void)in_sizes; (void)n_in; (void)out_size; (void)ws_size;

    const float* x     = (const float*)d_in[0];
    const float* Wqkv  = (const float*)d_in[1];
    const float* out_w = (const float*)d_in[2];
    const float* out_b = (const float*)d_in[3];
    float* out = (float*)d_out;

    unsigned short* qkvb  = (unsigned short*)d_ws;          // 8192*1536 bf16
    unsigned short* attnb = qkvb + (size_t)8192 * 1536;     // 8192*512  bf16
    unsigned short* xb    = attnb + (size_t)8192 * 512;     // 8192*512  bf16
    unsigned short* wqkvb = xb + (size_t)8192 * 512;        // 1536*512  bf16
    unsigned short* outwb = wqkvb + (size_t)1536 * 512;     // 512*512   bf16

    // 0) all fp32->bf16 conversions in one launch
    cvt_all<<<5120, 256, 0, stream>>>(x, Wqkv, out_w, xb, wqkvb, outwb);

    // 1) qkv = x @ Wqkv^T with fused RoPE + q-scale (bf16 out).
    //    Grid: x = 24 col-blocks (fastest), y = 64 row-blocks -> co-resident
    //    blocks share the A row-tile in L2.
    gemm_bt_mfma<<<dim3(24, 64), 256, 0, stream>>>(xb, wqkvb, nullptr, qkvb,
                                                   8192, 1536, 512, 1, 1);
    // 2) flash attention -> attnb bf16
    attn_mfma_kernel<<<dim3(32, 8, 4), 256, 0, stream>>>(qkvb, attnb);
    // 3) out = attn @ out_w^T + out_b (fp32 out)
    gemm_bt_mfma<<<dim3(8, 64), 256, 0, stream>>>(attnb, outwb, out_b, out,
                                                  8192, 512, 512, 0, 0);
}

// Round 12
// 139.146 us; speedup vs baseline: 1.1789x; 1.0271x over previous
//
#include <hip/hip_runtime.h>
#include <math.h>

// ---------------------------------------------------------------------------
// N=4, T=2048, D_MODEL=512, NHEAD=8, HEAD_DIM=64, window -127..+128.
// Pipeline: cvt_all -> bf16 ; qkv = x@Wqkv^T + fused RoPE + q-scale (MFMA,
// LDS-staged BM=128 BN=64 BK=64, XOR-swizzled, global_load_lds, R8 grid
// ordering: row-block-fastest) ; flash attn (MFMA, 2 query tiles per block:
// 6 staged K/V tiles serve 128 queries vs R8's 10 for the same) ; out GEMM.
// R11 lesson: col-fastest grid ordering regressed ~6 µs — reverted.
// ---------------------------------------------------------------------------

typedef __attribute__((ext_vector_type(8))) __bf16 bf16x8;
typedef __attribute__((ext_vector_type(4))) float f32x4;

__device__ __forceinline__ unsigned short f2bf(float f) {
    unsigned int u = __float_as_uint(f);
    u += 0x7fffu + ((u >> 16) & 1u);
    return (unsigned short)(u >> 16);
}
__device__ __forceinline__ unsigned int packbf2(float a, float b) {
    unsigned int ua = __float_as_uint(a); ua += 0x7fffu + ((ua >> 16) & 1u);
    unsigned int ub = __float_as_uint(b); ub += 0x7fffu + ((ub >> 16) & 1u);
    return (ua >> 16) | (ub & 0xffff0000u);
}
__device__ __forceinline__ bf16x8 as_bf16x8(uint4 u) {
    union { uint4 u4; bf16x8 v; } c; c.u4 = u; return c.v;
}
__device__ __forceinline__ bf16x8 ld_frag(const unsigned short* p) {
    return as_bf16x8(*(const uint4*)p);
}

__device__ __forceinline__ void async16(void* lds, const void* g) {
    __builtin_amdgcn_global_load_lds(
        (const __attribute__((address_space(1))) void*)g,
        (__attribute__((address_space(3))) void*)lds,
        16, 0, 0);
}

// One kernel converts all three fp32 inputs to bf16 (4 elems/thread).
__global__ __launch_bounds__(256) void cvt_all(
    const float* __restrict__ x, const float* __restrict__ w1,
    const float* __restrict__ w2,
    unsigned short* __restrict__ xb, unsigned short* __restrict__ w1b,
    unsigned short* __restrict__ w2b)
{
    const int n_x  = 8192 * 512 / 4;
    const int n_w1 = 1536 * 512 / 4;
    const int n_w2 = 512 * 512 / 4;
    int i = blockIdx.x * 256 + threadIdx.x;
    const float* in; unsigned short* out; int j;
    if (i < n_x)                    { in = x;  out = xb;  j = i; }
    else if (i < n_x + n_w1)        { in = w1; out = w1b; j = i - n_x; }
    else if (i < n_x + n_w1 + n_w2) { in = w2; out = w2b; j = i - n_x - n_w1; }
    else return;
    float4 v = *(const float4*)(in + 4 * (size_t)j);
    uint2 o;
    o.x = packbf2(v.x, v.y);
    o.y = packbf2(v.z, v.w);
    *(uint2*)(out + 4 * (size_t)j) = o;
}

// C[M,O] = A[M,K](bf16) * B[O,K](bf16)^T (+bias). Output fp32 or bf16.
// BM=128, BN=64, BK=64. Block=256 (4 waves); wave w computes rows
// [w*32,+32) x all 64 cols (mt=2, nt=4; acc 32 AGPR). R8 grid ordering:
// blockIdx.x = ROW block (fastest), .y = COL block.
// LDS XOR-swizzled k-offset: staging dests stay chunk-contiguous
// (global_load_lds constraint), frag reads conflict-free.
// do_rope: qkv layout (O=1536); RoPE cols<1024 (partner col^32 == acc nt^2,
// same thread), fold 1/8 into q cols<512.
__global__ __launch_bounds__(256) void gemm_bt_mfma(
    const unsigned short* __restrict__ A, const unsigned short* __restrict__ B,
    const float* __restrict__ bias, void* __restrict__ Cout,
    int M, int O, int K, int write_bf16, int do_rope)
{
    __shared__ __align__(16) unsigned short As[128 * 64];   // 16 KB
    __shared__ __align__(16) unsigned short Bs[64 * 64];    // 8 KB

    const int tid  = threadIdx.x;
    const int wave = tid >> 6;
    const int lane = tid & 63;
    const int l15  = lane & 15;
    const int lg   = lane >> 4;
    const int row0 = blockIdx.x * 128;
    const int col0 = blockIdx.y * 64;
    const int wr   = wave * 32;

    f32x4 acc[2][4] = {};

    const int srow = tid >> 3;
    const int skg  = ((tid & 7) * 8) ^ ((srow & 7) * 8);
    const int fx   = (l15 & 7) * 8;

    for (int k0 = 0; k0 < K; k0 += 64) {
        #pragma unroll
        for (int s = 0; s < 4; ++s)
            async16(&As[(size_t)(s * 256 + tid) * 8],
                    A + (size_t)(row0 + s * 32 + srow) * K + k0 + skg);
        #pragma unroll
        for (int s = 0; s < 2; ++s)
            async16(&Bs[(size_t)(s * 256 + tid) * 8],
                    B + (size_t)(col0 + s * 32 + srow) * K + k0 + skg);
        __syncthreads();

        #pragma unroll
        for (int kstep = 0; kstep < 2; ++kstep) {
            const int kq = (kstep * 32 + lg * 8) ^ fx;
            bf16x8 af[2], bfr[4];
            #pragma unroll
            for (int mt = 0; mt < 2; ++mt)
                af[mt] = ld_frag(&As[(wr + mt * 16 + l15) * 64 + kq]);
            #pragma unroll
            for (int nt = 0; nt < 4; ++nt)
                bfr[nt] = ld_frag(&Bs[(nt * 16 + l15) * 64 + kq]);
            #pragma unroll
            for (int mt = 0; mt < 2; ++mt)
                #pragma unroll
                for (int nt = 0; nt < 4; ++nt)
                    acc[mt][nt] = __builtin_amdgcn_mfma_f32_16x16x32_bf16(
                        af[mt], bfr[nt], acc[mt][nt], 0, 0, 0);
        }
        __syncthreads();
    }

    const int qrow = lg * 4;

    // Fused RoPE: col = col0 + nt*16 + l15, col0 mult of 64 -> d = nt*16+l15.
    // i = d&31 -> (nt&1)*16+l15 ; partner d^32 = acc nt^2 (same thread).
    if (do_rope && col0 < 1024) {
        const float cfreq = 0.28782313662425574f;   // ln(10000)/32
        const float invf0 = __expf(-(float)l15 * cfreq);
        const float invf1 = __expf(-(float)(16 + l15) * cfreq);
        #pragma unroll
        for (int mt = 0; mt < 2; ++mt) {
            #pragma unroll
            for (int r = 0; r < 4; ++r) {
                const int t = (row0 + wr + mt * 16 + qrow + r) & 2047;
                #pragma unroll
                for (int p = 0; p < 2; ++p) {
                    float ang = (float)t * (p ? invf1 : invf0);
                    float s, c;
                    __sincosf(ang, &s, &c);
                    float a = acc[mt][p][r];       // d = p*16+l15 (< 32)
                    float b = acc[mt][p + 2][r];   // d = 32 + p*16+l15
                    acc[mt][p][r]     = a * c - b * s;
                    acc[mt][p + 2][r] = b * c + a * s;
                }
            }
        }
        if (col0 < 512) {   // q: fold softmax scale 1/sqrt(64)
            #pragma unroll
            for (int mt = 0; mt < 2; ++mt)
                #pragma unroll
                for (int nt = 0; nt < 4; ++nt)
                    #pragma unroll
                    for (int r = 0; r < 4; ++r)
                        acc[mt][nt][r] *= 0.125f;
        }
    }

    #pragma unroll
    for (int nt = 0; nt < 4; ++nt) {
        const int col = col0 + nt * 16 + l15;
        const float bv = bias ? bias[col] : 0.f;
        #pragma unroll
        for (int mt = 0; mt < 2; ++mt) {
            const int rowb = row0 + wr + mt * 16 + qrow;
            if (write_bf16) {
                unsigned short* C = (unsigned short*)Cout;
                #pragma unroll
                for (int r = 0; r < 4; ++r)
                    C[(size_t)(rowb + r) * O + col] = f2bf(acc[mt][nt][r] + bv);
            } else {
                float* C = (float*)Cout;
                #pragma unroll
                for (int r = 0; r < 4; ++r)
                    C[(size_t)(rowb + r) * O + col] = acc[mt][nt][r] + bv;
            }
        }
    }
}

// Flash attention with MFMA, 2 query tiles per block. Block=256 (4 waves)
// handles (qb, h, n): queries [qb*128, qb*128+128). Key tiles kt = 2qb-2..
// 2qb+3 staged once each, used by both q-subtiles where in window.
// dt = kk-2-j is compile-time const per unrolled (kk, j) -> wave-uniform
// skips. 3 barriers per staged tile amortized over 2 q-subtiles.
// q pre-scaled by 1/8 in the QKV GEMM epilogue.
__global__ __launch_bounds__(256) void attn_mfma_kernel(
    const unsigned short* __restrict__ qkv, unsigned short* __restrict__ attnout)
{
    __shared__ __align__(16) unsigned short Kt[64 * 72];         // [key][dim]
    __shared__ __align__(16) unsigned short Vt[64 * 72];         // [dim][key]
    __shared__ __align__(16) unsigned short Ps[2][4][16 * 72];   // [qsub][wave]

    const int qb = blockIdx.x;    // 0..15
    const int h  = blockIdx.y;
    const int n  = blockIdx.z;
    const int tid  = threadIdx.x;
    const int wave = tid >> 6;
    const int lane = tid & 63;
    const int l15  = lane & 15;
    const int lg   = lane >> 4;

    const size_t base = (size_t)n * 2048 * 1536 + (size_t)h * 64;

    bf16x8 qfrag[2][2];
    #pragma unroll
    for (int j = 0; j < 2; ++j) {
        const int tq = (2 * qb + j) * 64 + wave * 16 + l15;
        const unsigned short* qp = qkv + base + (size_t)tq * 1536;
        qfrag[j][0] = ld_frag(qp + lg * 8);
        qfrag[j][1] = ld_frag(qp + 32 + lg * 8);
    }

    const int skey = tid >> 2;
    const int sd0  = (tid & 3) * 16;

    float m_r[2][4], l_r[2][4];
    #pragma unroll
    for (int j = 0; j < 2; ++j)
        #pragma unroll
        for (int r = 0; r < 4; ++r) { m_r[j][r] = -1e30f; l_r[j][r] = 0.f; }
    f32x4 acc_o[2][4] = {};

    #pragma unroll
    for (int kk = 0; kk < 6; ++kk) {
        const int kt = 2 * qb - 2 + kk;
        if (kt < 0 || kt > 31) continue;   // block-uniform
        const int s0 = kt * 64;

        {   // stage K (copy) + V (transpose)
            const unsigned short* kp = qkv + base + 512 + (size_t)(s0 + skey) * 1536 + sd0;
            uint4 k0 = *(const uint4*)kp;
            uint4 k1 = *(const uint4*)(kp + 8);
            *(uint4*)&Kt[skey * 72 + sd0]     = k0;
            *(uint4*)&Kt[skey * 72 + sd0 + 8] = k1;

            const unsigned short* vp = qkv + base + 1024 + (size_t)(s0 + skey) * 1536 + sd0;
            uint4 a = *(const uint4*)vp;
            uint4 b = *(const uint4*)(vp + 8);
            Vt[(sd0 +  0) * 72 + skey] = (unsigned short)(a.x & 0xffffu);
            Vt[(sd0 +  1) * 72 + skey] = (unsigned short)(a.x >> 16);
            Vt[(sd0 +  2) * 72 + skey] = (unsigned short)(a.y & 0xffffu);
            Vt[(sd0 +  3) * 72 + skey] = (unsigned short)(a.y >> 16);
            Vt[(sd0 +  4) * 72 + skey] = (unsigned short)(a.z & 0xffffu);
            Vt[(sd0 +  5) * 72 + skey] = (unsigned short)(a.z >> 16);
            Vt[(sd0 +  6) * 72 + skey] = (unsigned short)(a.w & 0xffffu);
            Vt[(sd0 +  7) * 72 + skey] = (unsigned short)(a.w >> 16);
            Vt[(sd0 +  8) * 72 + skey] = (unsigned short)(b.x & 0xffffu);
            Vt[(sd0 +  9) * 72 + skey] = (unsigned short)(b.x >> 16);
            Vt[(sd0 + 10) * 72 + skey] = (unsigned short)(b.y & 0xffffu);
            Vt[(sd0 + 11) * 72 + skey] = (unsigned short)(b.y >> 16);
            Vt[(sd0 + 12) * 72 + skey] = (unsigned short)(b.z & 0xffffu);
            Vt[(sd0 + 13) * 72 + skey] = (unsigned short)(b.z >> 16);
            Vt[(sd0 + 14) * 72 + skey] = (unsigned short)(b.w & 0xffffu);
            Vt[(sd0 + 15) * 72 + skey] = (unsigned short)(b.w >> 16);
        }
        __syncthreads();   // barrier 1: staging visible

        // ---- per q-subtile: QK^T + softmax + Ps write ----
        #pragma unroll
        for (int j = 0; j < 2; ++j) {
            const int dt = kk - 2 - j;            // compile-time const
            if (dt < -2 || dt > 2) continue;

            f32x4 acc_s[4] = {};
            #pragma unroll
            for (int kstep = 0; kstep < 2; ++kstep) {
                #pragma unroll
                for (int nt = 0; nt < 4; ++nt) {
                    if ((dt == -2 && nt < wave) || (dt == 2 && nt > wave))
                        continue;   // fully-masked edge sub-tile
                    bf16x8 kf = ld_frag(&Kt[(nt * 16 + l15) * 72 + kstep * 32 + lg * 8]);
                    acc_s[nt] = __builtin_amdgcn_mfma_f32_16x16x32_bf16(
                        qfrag[j][kstep], kf, acc_s[nt], 0, 0, 0);
                }
            }

            float sc[4][4];
            #pragma unroll
            for (int nt = 0; nt < 4; ++nt) {
                const int key_off = dt * 64 + nt * 16 + l15;
                #pragma unroll
                for (int r = 0; r < 4; ++r) {
                    const int diff = key_off - (wave * 16 + lg * 4 + r);
                    const bool ok = (diff >= -127) && (diff <= 128);
                    sc[nt][r] = ok ? acc_s[nt][r] : -1e30f;
                }
            }
            #pragma unroll
            for (int r = 0; r < 4; ++r) {
                float tm = fmaxf(fmaxf(sc[0][r], sc[1][r]), fmaxf(sc[2][r], sc[3][r]));
                tm = fmaxf(tm, __shfl_xor(tm, 1, 64));
                tm = fmaxf(tm, __shfl_xor(tm, 2, 64));
                tm = fmaxf(tm, __shfl_xor(tm, 4, 64));
                tm = fmaxf(tm, __shfl_xor(tm, 8, 64));
                const float m_new = fmaxf(m_r[j][r], tm);
                const float alpha = __expf(m_r[j][r] - m_new);
                float psum = 0.f;
                #pragma unroll
                for (int nt = 0; nt < 4; ++nt) {
                    float p = __expf(sc[nt][r] - m_new);
                    sc[nt][r] = p;
                    psum += p;
                }
                psum += __shfl_xor(psum, 1, 64);
                psum += __shfl_xor(psum, 2, 64);
                psum += __shfl_xor(psum, 4, 64);
                psum += __shfl_xor(psum, 8, 64);
                l_r[j][r] = l_r[j][r] * alpha + psum;
                m_r[j][r] = m_new;
                #pragma unroll
                for (int nt = 0; nt < 4; ++nt) acc_o[j][nt][r] *= alpha;
            }

            #pragma unroll
            for (int nt = 0; nt < 4; ++nt)
                #pragma unroll
                for (int r = 0; r < 4; ++r)
                    Ps[j][wave][(lg * 4 + r) * 72 + nt * 16 + l15] = f2bf(sc[nt][r]);
        }
        __syncthreads();   // barrier 2: Ps visible, Kt reads done

        // ---- per q-subtile: O += P V ----
        #pragma unroll
        for (int j = 0; j < 2; ++j) {
            const int dt = kk - 2 - j;
            if (dt < -2 || dt > 2) continue;
            bf16x8 pfrag[2];
            pfrag[0] = ld_frag(&Ps[j][wave][l15 * 72 + lg * 8]);
            pfrag[1] = ld_frag(&Ps[j][wave][l15 * 72 + 32 + lg * 8]);
            #pragma unroll
            for (int kstep = 0; kstep < 2; ++kstep) {
                #pragma unroll
                for (int nt = 0; nt < 4; ++nt) {
                    bf16x8 vf = ld_frag(&Vt[(nt * 16 + l15) * 72 + kstep * 32 + lg * 8]);
                    acc_o[j][nt] = __builtin_amdgcn_mfma_f32_16x16x32_bf16(
                        pfrag[kstep], vf, acc_o[j][nt], 0, 0, 0);
                }
            }
        }
        __syncthreads();   // barrier 3: Vt/Ps reads done before next staging
    }

    #pragma unroll
    for (int j = 0; j < 2; ++j) {
        float inv_l[4];
        #pragma unroll
        for (int r = 0; r < 4; ++r) inv_l[r] = 1.0f / l_r[j][r];
        #pragma unroll
        for (int r = 0; r < 4; ++r) {
            const int tq = (2 * qb + j) * 64 + wave * 16 + lg * 4 + r;
            unsigned short* op = attnout + (size_t)(n * 2048 + tq) * 512 + h * 64;
            #pragma unroll
            for (int nt = 0; nt < 4; ++nt)
                op[nt * 16 + l15] = f2bf(acc_o[j][nt][r] * inv_l[r]);
        }
    }
}

extern "C" void kernel_launch(void* const* d_in, const int* in_sizes, int n_in,
                              void* d_out, int out_size, void* d_ws, size_t ws_size,
                              hipStream_t stream)
{
    (void)in_sizes; (void)n_in; (void)out_size; (void)ws_size;

    const float* x     = (const float*)d_in[0];
    const float* Wqkv  = (const float*)d_in[1];
    const float* out_w = (const float*)d_in[2];
    const float* out_b = (const float*)d_in[3];
    float* out = (float*)d_out;

    unsigned short* qkvb  = (unsigned short*)d_ws;          // 8192*1536 bf16
    unsigned short* attnb = qkvb + (size_t)8192 * 1536;     // 8192*512  bf16
    unsigned short* xb    = attnb + (size_t)8192 * 512;     // 8192*512  bf16
    unsigned short* wqkvb = xb + (size_t)8192 * 512;        // 1536*512  bf16
    unsigned short* outwb = wqkvb + (size_t)1536 * 512;     // 512*512   bf16

    // 0) all fp32->bf16 conversions in one launch
    cvt_all<<<5120, 256, 0, stream>>>(x, Wqkv, out_w, xb, wqkvb, outwb);

    // 1) qkv = x @ Wqkv^T with fused RoPE + q-scale (bf16 out). R8 ordering.
    gemm_bt_mfma<<<dim3(64, 24), 256, 0, stream>>>(xb, wqkvb, nullptr, qkvb,
                                                   8192, 1536, 512, 1, 1);
    // 2) flash attention (2 q-tiles/block) -> attnb bf16
    attn_mfma_kernel<<<dim3(16, 8, 4), 256, 0, stream>>>(qkvb, attnb);
    // 3) out = attn @ out_w^T + out_b (fp32 out)
    gemm_bt_mfma<<<dim3(64, 8), 256, 0, stream>>>(attnb, outwb, out_b, out,
                                                  8192, 512, 512, 0, 0);
}

// Round 13
// 135.450 us; speedup vs baseline: 1.2111x; 1.0273x over previous
//
#include <hip/hip_runtime.h>
#include <math.h>

// ---------------------------------------------------------------------------
// N=4, T=2048, D_MODEL=512, NHEAD=8, HEAD_DIM=64, window -127..+128.
// Pipeline: cvt_all -> bf16 ; qkv = x@Wqkv^T + fused RoPE + q-scale (MFMA,
// LDS-staged BM=128 BN=64 BK=64, XOR-swizzled, global_load_lds) ; flash attn
// (MFMA, R8 single-q-tile form + edge-subtile skip) ; out GEMM.
// R13: __launch_bounds__(256,5) on the GEMM to force ~5 blocks/CU (both pipes
// idle at ~2.7 blocks/CU; barrier drains need more resident blocks to hide).
// R12 lesson: 2-q-tile attn staging reuse was neutral/negative — reverted.
// ---------------------------------------------------------------------------

typedef __attribute__((ext_vector_type(8))) __bf16 bf16x8;
typedef __attribute__((ext_vector_type(4))) float f32x4;

__device__ __forceinline__ unsigned short f2bf(float f) {
    unsigned int u = __float_as_uint(f);
    u += 0x7fffu + ((u >> 16) & 1u);
    return (unsigned short)(u >> 16);
}
__device__ __forceinline__ unsigned int packbf2(float a, float b) {
    unsigned int ua = __float_as_uint(a); ua += 0x7fffu + ((ua >> 16) & 1u);
    unsigned int ub = __float_as_uint(b); ub += 0x7fffu + ((ub >> 16) & 1u);
    return (ua >> 16) | (ub & 0xffff0000u);
}
__device__ __forceinline__ bf16x8 as_bf16x8(uint4 u) {
    union { uint4 u4; bf16x8 v; } c; c.u4 = u; return c.v;
}
__device__ __forceinline__ bf16x8 ld_frag(const unsigned short* p) {
    return as_bf16x8(*(const uint4*)p);
}

__device__ __forceinline__ void async16(void* lds, const void* g) {
    __builtin_amdgcn_global_load_lds(
        (const __attribute__((address_space(1))) void*)g,
        (__attribute__((address_space(3))) void*)lds,
        16, 0, 0);
}

// One kernel converts all three fp32 inputs to bf16 (4 elems/thread).
__global__ __launch_bounds__(256) void cvt_all(
    const float* __restrict__ x, const float* __restrict__ w1,
    const float* __restrict__ w2,
    unsigned short* __restrict__ xb, unsigned short* __restrict__ w1b,
    unsigned short* __restrict__ w2b)
{
    const int n_x  = 8192 * 512 / 4;
    const int n_w1 = 1536 * 512 / 4;
    const int n_w2 = 512 * 512 / 4;
    int i = blockIdx.x * 256 + threadIdx.x;
    const float* in; unsigned short* out; int j;
    if (i < n_x)                    { in = x;  out = xb;  j = i; }
    else if (i < n_x + n_w1)        { in = w1; out = w1b; j = i - n_x; }
    else if (i < n_x + n_w1 + n_w2) { in = w2; out = w2b; j = i - n_x - n_w1; }
    else return;
    float4 v = *(const float4*)(in + 4 * (size_t)j);
    uint2 o;
    o.x = packbf2(v.x, v.y);
    o.y = packbf2(v.z, v.w);
    *(uint2*)(out + 4 * (size_t)j) = o;
}

// C[M,O] = A[M,K](bf16) * B[O,K](bf16)^T (+bias). Output fp32 or bf16.
// BM=128, BN=64, BK=64. Block=256 (4 waves); wave w computes rows
// [w*32,+32) x all 64 cols (mt=2, nt=4; acc 32 AGPR).
// __launch_bounds__(256,5): target 5 blocks/CU (~102-reg cap) so barrier
// drains overlap across resident blocks.
// Grid: blockIdx.x = ROW block (fastest; R11 showed col-fastest regresses).
// LDS XOR-swizzled k-offset: staging dests stay chunk-contiguous
// (global_load_lds constraint), frag reads conflict-free.
// do_rope: qkv layout (O=1536); RoPE cols<1024 (partner col^32 == acc nt^2,
// same thread), fold 1/8 into q cols<512.
__global__ __launch_bounds__(256, 5) void gemm_bt_mfma(
    const unsigned short* __restrict__ A, const unsigned short* __restrict__ B,
    const float* __restrict__ bias, void* __restrict__ Cout,
    int M, int O, int K, int write_bf16, int do_rope)
{
    __shared__ __align__(16) unsigned short As[128 * 64];   // 16 KB
    __shared__ __align__(16) unsigned short Bs[64 * 64];    // 8 KB

    const int tid  = threadIdx.x;
    const int wave = tid >> 6;
    const int lane = tid & 63;
    const int l15  = lane & 15;
    const int lg   = lane >> 4;
    const int row0 = blockIdx.x * 128;
    const int col0 = blockIdx.y * 64;
    const int wr   = wave * 32;

    f32x4 acc[2][4] = {};

    const int srow = tid >> 3;
    const int skg  = ((tid & 7) * 8) ^ ((srow & 7) * 8);
    const int fx   = (l15 & 7) * 8;

    for (int k0 = 0; k0 < K; k0 += 64) {
        #pragma unroll
        for (int s = 0; s < 4; ++s)
            async16(&As[(size_t)(s * 256 + tid) * 8],
                    A + (size_t)(row0 + s * 32 + srow) * K + k0 + skg);
        #pragma unroll
        for (int s = 0; s < 2; ++s)
            async16(&Bs[(size_t)(s * 256 + tid) * 8],
                    B + (size_t)(col0 + s * 32 + srow) * K + k0 + skg);
        __syncthreads();

        #pragma unroll
        for (int kstep = 0; kstep < 2; ++kstep) {
            const int kq = (kstep * 32 + lg * 8) ^ fx;
            bf16x8 af[2], bfr[4];
            #pragma unroll
            for (int mt = 0; mt < 2; ++mt)
                af[mt] = ld_frag(&As[(wr + mt * 16 + l15) * 64 + kq]);
            #pragma unroll
            for (int nt = 0; nt < 4; ++nt)
                bfr[nt] = ld_frag(&Bs[(nt * 16 + l15) * 64 + kq]);
            #pragma unroll
            for (int mt = 0; mt < 2; ++mt)
                #pragma unroll
                for (int nt = 0; nt < 4; ++nt)
                    acc[mt][nt] = __builtin_amdgcn_mfma_f32_16x16x32_bf16(
                        af[mt], bfr[nt], acc[mt][nt], 0, 0, 0);
        }
        __syncthreads();
    }

    const int qrow = lg * 4;

    // Fused RoPE: col = col0 + nt*16 + l15, col0 mult of 64 -> d = nt*16+l15.
    // i = d&31 -> (nt&1)*16+l15 ; partner d^32 = acc nt^2 (same thread).
    if (do_rope && col0 < 1024) {
        const float cfreq = 0.28782313662425574f;   // ln(10000)/32
        const float invf0 = __expf(-(float)l15 * cfreq);
        const float invf1 = __expf(-(float)(16 + l15) * cfreq);
        #pragma unroll
        for (int mt = 0; mt < 2; ++mt) {
            #pragma unroll
            for (int r = 0; r < 4; ++r) {
                const int t = (row0 + wr + mt * 16 + qrow + r) & 2047;
                #pragma unroll
                for (int p = 0; p < 2; ++p) {
                    float ang = (float)t * (p ? invf1 : invf0);
                    float s, c;
                    __sincosf(ang, &s, &c);
                    float a = acc[mt][p][r];       // d = p*16+l15 (< 32)
                    float b = acc[mt][p + 2][r];   // d = 32 + p*16+l15
                    acc[mt][p][r]     = a * c - b * s;
                    acc[mt][p + 2][r] = b * c + a * s;
                }
            }
        }
        if (col0 < 512) {   // q: fold softmax scale 1/sqrt(64)
            #pragma unroll
            for (int mt = 0; mt < 2; ++mt)
                #pragma unroll
                for (int nt = 0; nt < 4; ++nt)
                    #pragma unroll
                    for (int r = 0; r < 4; ++r)
                        acc[mt][nt][r] *= 0.125f;
        }
    }

    #pragma unroll
    for (int nt = 0; nt < 4; ++nt) {
        const int col = col0 + nt * 16 + l15;
        const float bv = bias ? bias[col] : 0.f;
        #pragma unroll
        for (int mt = 0; mt < 2; ++mt) {
            const int rowb = row0 + wr + mt * 16 + qrow;
            if (write_bf16) {
                unsigned short* C = (unsigned short*)Cout;
                #pragma unroll
                for (int r = 0; r < 4; ++r)
                    C[(size_t)(rowb + r) * O + col] = f2bf(acc[mt][nt][r] + bv);
            } else {
                float* C = (float*)Cout;
                #pragma unroll
                for (int r = 0; r < 4; ++r)
                    C[(size_t)(rowb + r) * O + col] = acc[mt][nt][r] + bv;
            }
        }
    }
}

// Flash attention with MFMA (R8 structure + edge sub-tile skip). Block=256
// (4 waves) handles (qt, h, n). K staged (copy), V staged transposed; P via
// per-wave LDS slice. q pre-scaled by 1/8 in the QKV GEMM epilogue.
__global__ __launch_bounds__(256) void attn_mfma_kernel(
    const unsigned short* __restrict__ qkv, unsigned short* __restrict__ attnout)
{
    __shared__ __align__(16) unsigned short Kt[64 * 72];      // [key][dim]
    __shared__ __align__(16) unsigned short Vt[64 * 72];      // [dim][key]
    __shared__ __align__(16) unsigned short Ps[4][16 * 72];   // per-wave P

    const int qt = blockIdx.x;
    const int h  = blockIdx.y;
    const int n  = blockIdx.z;
    const int t0 = qt * 64;
    const int tid  = threadIdx.x;
    const int wave = tid >> 6;
    const int lane = tid & 63;
    const int l15  = lane & 15;
    const int lg   = lane >> 4;

    const size_t base = (size_t)n * 2048 * 1536 + (size_t)h * 64;

    bf16x8 qfrag[2];
    {
        const unsigned short* qp = qkv + base + (size_t)(t0 + wave * 16 + l15) * 1536;
        qfrag[0] = ld_frag(qp + lg * 8);
        qfrag[1] = ld_frag(qp + 32 + lg * 8);
    }

    const int skey = tid >> 2;
    const int sd0  = (tid & 3) * 16;

    float m_r[4], l_r[4];
    #pragma unroll
    for (int r = 0; r < 4; ++r) { m_r[r] = -1e30f; l_r[r] = 0.f; }
    f32x4 acc_o[4] = {};

    for (int dt = -2; dt <= 2; ++dt) {
        const int kt = qt + dt;
        if (kt < 0 || kt > 31) continue;
        const int s0 = kt * 64;

        {   // stage K (copy) + V (transpose)
            const unsigned short* kp = qkv + base + 512 + (size_t)(s0 + skey) * 1536 + sd0;
            uint4 k0 = *(const uint4*)kp;
            uint4 k1 = *(const uint4*)(kp + 8);
            *(uint4*)&Kt[skey * 72 + sd0]     = k0;
            *(uint4*)&Kt[skey * 72 + sd0 + 8] = k1;

            const unsigned short* vp = qkv + base + 1024 + (size_t)(s0 + skey) * 1536 + sd0;
            uint4 a = *(const uint4*)vp;
            uint4 b = *(const uint4*)(vp + 8);
            Vt[(sd0 +  0) * 72 + skey] = (unsigned short)(a.x & 0xffffu);
            Vt[(sd0 +  1) * 72 + skey] = (unsigned short)(a.x >> 16);
            Vt[(sd0 +  2) * 72 + skey] = (unsigned short)(a.y & 0xffffu);
            Vt[(sd0 +  3) * 72 + skey] = (unsigned short)(a.y >> 16);
            Vt[(sd0 +  4) * 72 + skey] = (unsigned short)(a.z & 0xffffu);
            Vt[(sd0 +  5) * 72 + skey] = (unsigned short)(a.z >> 16);
            Vt[(sd0 +  6) * 72 + skey] = (unsigned short)(a.w & 0xffffu);
            Vt[(sd0 +  7) * 72 + skey] = (unsigned short)(a.w >> 16);
            Vt[(sd0 +  8) * 72 + skey] = (unsigned short)(b.x & 0xffffu);
            Vt[(sd0 +  9) * 72 + skey] = (unsigned short)(b.x >> 16);
            Vt[(sd0 + 10) * 72 + skey] = (unsigned short)(b.y & 0xffffu);
            Vt[(sd0 + 11) * 72 + skey] = (unsigned short)(b.y >> 16);
            Vt[(sd0 + 12) * 72 + skey] = (unsigned short)(b.z & 0xffffu);
            Vt[(sd0 + 13) * 72 + skey] = (unsigned short)(b.z >> 16);
            Vt[(sd0 + 14) * 72 + skey] = (unsigned short)(b.w & 0xffffu);
            Vt[(sd0 + 15) * 72 + skey] = (unsigned short)(b.w >> 16);
        }
        __syncthreads();

        // ---- S = Q K^T (skip fully-masked edge sub-tiles) ----
        f32x4 acc_s[4] = {};
        #pragma unroll
        for (int kstep = 0; kstep < 2; ++kstep) {
            #pragma unroll
            for (int nt = 0; nt < 4; ++nt) {
                if ((dt == -2 && nt < wave) || (dt == 2 && nt > wave)) continue;
                bf16x8 kf = ld_frag(&Kt[(nt * 16 + l15) * 72 + kstep * 32 + lg * 8]);
                acc_s[nt] = __builtin_amdgcn_mfma_f32_16x16x32_bf16(
                    qfrag[kstep], kf, acc_s[nt], 0, 0, 0);
            }
        }

        float sc[4][4];
        #pragma unroll
        for (int nt = 0; nt < 4; ++nt) {
            const int key_off = dt * 64 + nt * 16 + l15;
            #pragma unroll
            for (int r = 0; r < 4; ++r) {
                const int diff = key_off - (wave * 16 + lg * 4 + r);
                const bool ok = (diff >= -127) && (diff <= 128);
                sc[nt][r] = ok ? acc_s[nt][r] : -1e30f;   // scale folded into q
            }
        }
        #pragma unroll
        for (int r = 0; r < 4; ++r) {
            float tm = fmaxf(fmaxf(sc[0][r], sc[1][r]), fmaxf(sc[2][r], sc[3][r]));
            tm = fmaxf(tm, __shfl_xor(tm, 1, 64));
            tm = fmaxf(tm, __shfl_xor(tm, 2, 64));
            tm = fmaxf(tm, __shfl_xor(tm, 4, 64));
            tm = fmaxf(tm, __shfl_xor(tm, 8, 64));
            const float m_new = fmaxf(m_r[r], tm);
            const float alpha = __expf(m_r[r] - m_new);
            float psum = 0.f;
            #pragma unroll
            for (int nt = 0; nt < 4; ++nt) {
                float p = __expf(sc[nt][r] - m_new);
                sc[nt][r] = p;
                psum += p;
            }
            psum += __shfl_xor(psum, 1, 64);
            psum += __shfl_xor(psum, 2, 64);
            psum += __shfl_xor(psum, 4, 64);
            psum += __shfl_xor(psum, 8, 64);
            l_r[r] = l_r[r] * alpha + psum;
            m_r[r] = m_new;
            #pragma unroll
            for (int nt = 0; nt < 4; ++nt) acc_o[nt][r] *= alpha;
        }

        #pragma unroll
        for (int nt = 0; nt < 4; ++nt)
            #pragma unroll
            for (int r = 0; r < 4; ++r)
                Ps[wave][(lg * 4 + r) * 72 + nt * 16 + l15] = f2bf(sc[nt][r]);

        __syncthreads();

        bf16x8 pfrag[2];
        pfrag[0] = ld_frag(&Ps[wave][l15 * 72 + lg * 8]);
        pfrag[1] = ld_frag(&Ps[wave][l15 * 72 + 32 + lg * 8]);

        #pragma unroll
        for (int kstep = 0; kstep < 2; ++kstep) {
            #pragma unroll
            for (int nt = 0; nt < 4; ++nt) {
                bf16x8 vf = ld_frag(&Vt[(nt * 16 + l15) * 72 + kstep * 32 + lg * 8]);
                acc_o[nt] = __builtin_amdgcn_mfma_f32_16x16x32_bf16(
                    pfrag[kstep], vf, acc_o[nt], 0, 0, 0);
            }
        }
        __syncthreads();
    }

    float inv_l[4];
    #pragma unroll
    for (int r = 0; r < 4; ++r) inv_l[r] = 1.0f / l_r[r];

    #pragma unroll
    for (int r = 0; r < 4; ++r) {
        const int tq = t0 + wave * 16 + lg * 4 + r;
        unsigned short* op = attnout + (size_t)(n * 2048 + tq) * 512 + h * 64;
        #pragma unroll
        for (int nt = 0; nt < 4; ++nt)
            op[nt * 16 + l15] = f2bf(acc_o[nt][r] * inv_l[r]);
    }
}

extern "C" void kernel_launch(void* const* d_in, const int* in_sizes, int n_in,
                              void* d_out, int out_size, void* d_ws, size_t ws_size,
                              hipStream_t stream)
{
    (void)in_sizes; (void)n_in; (void)out_size; (void)ws_size;

    const float* x     = (const float*)d_in[0];
    const float* Wqkv  = (const float*)d_in[1];
    const float* out_w = (const float*)d_in[2];
    const float* out_b = (const float*)d_in[3];
    float* out = (float*)d_out;

    unsigned short* qkvb  = (unsigned short*)d_ws;          // 8192*1536 bf16
    unsigned short* attnb = qkvb + (size_t)8192 * 1536;     // 8192*512  bf16
    unsigned short* xb    = attnb + (size_t)8192 * 512;     // 8192*512  bf16
    unsigned short* wqkvb = xb + (size_t)8192 * 512;        // 1536*512  bf16
    unsigned short* outwb = wqkvb + (size_t)1536 * 512;     // 512*512   bf16

    // 0) all fp32->bf16 conversions in one launch
    cvt_all<<<5120, 256, 0, stream>>>(x, Wqkv, out_w, xb, wqkvb, outwb);

    // 1) qkv = x @ Wqkv^T with fused RoPE + q-scale (bf16 out)
    gemm_bt_mfma<<<dim3(64, 24), 256, 0, stream>>>(xb, wqkvb, nullptr, qkvb,
                                                   8192, 1536, 512, 1, 1);
    // 2) flash attention -> attnb bf16
    attn_mfma_kernel<<<dim3(32, 8, 4), 256, 0, stream>>>(qkvb, attnb);
    // 3) out = attn @ out_w^T + out_b (fp32 out)
    gemm_bt_mfma<<<dim3(64, 8), 256, 0, stream>>>(attnb, outwb, out_b, out,
                                                  8192, 512, 512, 0, 0);
}